// Round 1
// baseline (1821.320 us; speedup 1.0000x reference)
//
#include <hip/hip_runtime.h>
#include <hip/hip_bf16.h>

#define NUM_VOXELS_CONST 200000
#define CHANNELS 32

// Scatter-add: one thread per (point, quad-of-4-channels).
// Consecutive threads read consecutive float4s -> fully coalesced 16B/lane.
__global__ void vfe_scatter_kernel(const float* __restrict__ feat,
                                   const int* __restrict__ index,
                                   float* __restrict__ sums,
                                   float* __restrict__ counts,
                                   int n_points) {
    const long long total = (long long)n_points * 8;       // 8 quads per point
    const long long stride = (long long)gridDim.x * blockDim.x;
    for (long long t = (long long)blockIdx.x * blockDim.x + threadIdx.x;
         t < total; t += stride) {
        const int p = (int)(t >> 3);
        const int q = (int)(t & 7);
        const int v = index[p];
        if (v < 0) continue;                               // masked-out point
        const float4 f = reinterpret_cast<const float4*>(feat)[(long long)p * 8 + q];
        float* dst = sums + (long long)v * CHANNELS + q * 4;
        atomicAdd(dst + 0, f.x);
        atomicAdd(dst + 1, f.y);
        atomicAdd(dst + 2, f.z);
        atomicAdd(dst + 3, f.w);
        if (q == 0) atomicAdd(counts + v, 1.0f);
    }
}

// Finalize: sums[v][c] /= max(counts[v], 1). Vectorized float4.
__global__ void vfe_finalize_kernel(float* __restrict__ sums,
                                    const float* __restrict__ counts,
                                    int num_voxels) {
    const int total = num_voxels * 8;                      // float4 groups
    const int stride = gridDim.x * blockDim.x;
    for (int t = blockIdx.x * blockDim.x + threadIdx.x; t < total; t += stride) {
        const int v = t >> 3;
        const float c = fmaxf(counts[v], 1.0f);
        const float inv = 1.0f / c;
        float4 s = reinterpret_cast<float4*>(sums)[t];
        s.x *= inv; s.y *= inv; s.z *= inv; s.w *= inv;
        reinterpret_cast<float4*>(sums)[t] = s;
    }
}

extern "C" void kernel_launch(void* const* d_in, const int* in_sizes, int n_in,
                              void* d_out, int out_size, void* d_ws, size_t ws_size,
                              hipStream_t stream) {
    const float* feat = (const float*)d_in[0];   // (N, 32) fp32
    const int* index = (const int*)d_in[1];      // (N,) int (harness downcasts int64)
    const int n_points = in_sizes[1];            // N = 4,000,000

    float* sums = (float*)d_out;                 // (200000, 32) fp32
    float* counts = (float*)d_ws;                // 200000 fp32 in workspace

    // Zero accumulators every call (harness poisons but does not re-zero).
    hipMemsetAsync(sums, 0, (size_t)NUM_VOXELS_CONST * CHANNELS * sizeof(float), stream);
    hipMemsetAsync(counts, 0, (size_t)NUM_VOXELS_CONST * sizeof(float), stream);

    const int block = 256;
    const int grid_scatter = 4096;               // grid-stride over 32M quads
    vfe_scatter_kernel<<<grid_scatter, block, 0, stream>>>(
        feat, index, sums, counts, n_points);

    const int grid_fin = (NUM_VOXELS_CONST * 8 + block - 1) / block;
    vfe_finalize_kernel<<<grid_fin, block, 0, stream>>>(
        sums, counts, NUM_VOXELS_CONST);
}

// Round 2
// 746.801 us; speedup vs baseline: 2.4388x; 2.4388x over previous
//
#include <hip/hip_runtime.h>
#include <hip/hip_bf16.h>

#define NV 200000                 // num_voxels (reference constant)
#define CH 32                     // channels
#define SCAN_CHUNK 2048
#define NSCAN_BLOCKS ((NV + SCAN_CHUNK - 1) / SCAN_CHUNK)   // 98
static_assert(NSCAN_BLOCKS <= 128, "scan2 assumes <=128 partials");

// ---------------- fast path: counting-sort + gather ----------------

// Pass 1: per-voxel histogram (int atomics), int4-vectorized index reads.
__global__ void vfe_hist_kernel(const int* __restrict__ index,
                                int* __restrict__ cnt, int n) {
    const int n4 = n >> 2;
    const int stride = gridDim.x * blockDim.x;
    for (int t = blockIdx.x * blockDim.x + threadIdx.x; t < n4; t += stride) {
        int4 v = reinterpret_cast<const int4*>(index)[t];
        if (v.x >= 0) atomicAdd(&cnt[v.x], 1);
        if (v.y >= 0) atomicAdd(&cnt[v.y], 1);
        if (v.z >= 0) atomicAdd(&cnt[v.z], 1);
        if (v.w >= 0) atomicAdd(&cnt[v.w], 1);
    }
    if (blockIdx.x == 0 && threadIdx.x == 0) {
        for (int i = n4 << 2; i < n; ++i) {
            int v = index[i];
            if (v >= 0) atomicAdd(&cnt[v], 1);
        }
    }
}

// Pass 2a: per-chunk exclusive scan (chunk=2048, block=256, 8 elems/thread).
__global__ void vfe_scan1_kernel(const int* __restrict__ cnt,
                                 int* __restrict__ offs,
                                 int* __restrict__ partials, int n) {
    __shared__ int lds[256];
    const int t = threadIdx.x;
    const int base = blockIdx.x * SCAN_CHUNK + t * 8;
    int pre[8];
    int sum = 0;
    #pragma unroll
    for (int j = 0; j < 8; ++j) {
        int e = base + j;
        int v = (e < n) ? cnt[e] : 0;
        pre[j] = sum;                 // exclusive prefix within thread
        sum += v;
    }
    lds[t] = sum;
    __syncthreads();
    for (int d = 1; d < 256; d <<= 1) {
        int x = (t >= d) ? lds[t - d] : 0;
        __syncthreads();
        lds[t] += x;
        __syncthreads();
    }
    const int thrExcl = (t > 0) ? lds[t - 1] : 0;
    if (t == 255) partials[blockIdx.x] = lds[255];
    #pragma unroll
    for (int j = 0; j < 8; ++j) {
        int e = base + j;
        if (e < n) offs[e] = thrExcl + pre[j];
    }
}

// Pass 2b: scan the 98 block partials (single block), write grand total.
__global__ void vfe_scan2_kernel(int* __restrict__ partials,
                                 int* __restrict__ total_slot, int nb) {
    __shared__ int lds[128];
    const int t = threadIdx.x;
    lds[t] = (t < nb) ? partials[t] : 0;
    __syncthreads();
    for (int d = 1; d < 128; d <<= 1) {
        int x = (t >= d) ? lds[t - d] : 0;
        __syncthreads();
        lds[t] += x;
        __syncthreads();
    }
    if (t < nb) partials[t] = (t > 0) ? lds[t - 1] : 0;   // exclusive
    if (t == 127) *total_slot = lds[127];                  // total valid points
}

// Pass 2c: add block offsets; duplicate into cursor for the permute pass.
__global__ void vfe_scan3_kernel(int* __restrict__ offs,
                                 int* __restrict__ cursor,
                                 const int* __restrict__ partials, int n) {
    int t = blockIdx.x * blockDim.x + threadIdx.x;
    if (t < n) {
        int v = offs[t] + partials[t / SCAN_CHUNK];
        offs[t] = v;
        cursor[t] = v;
    }
}

// Pass 3: scatter point ids into voxel-sorted order.
__global__ void vfe_permute_kernel(const int* __restrict__ index,
                                   int* __restrict__ cursor,
                                   int* __restrict__ sorted, int n) {
    const int n4 = n >> 2;
    const int stride = gridDim.x * blockDim.x;
    for (int t = blockIdx.x * blockDim.x + threadIdx.x; t < n4; t += stride) {
        int4 v = reinterpret_cast<const int4*>(index)[t];
        const int base = t << 2;
        if (v.x >= 0) sorted[atomicAdd(&cursor[v.x], 1)] = base;
        if (v.y >= 0) sorted[atomicAdd(&cursor[v.y], 1)] = base + 1;
        if (v.z >= 0) sorted[atomicAdd(&cursor[v.z], 1)] = base + 2;
        if (v.w >= 0) sorted[atomicAdd(&cursor[v.w], 1)] = base + 3;
    }
    if (blockIdx.x == 0 && threadIdx.x == 0) {
        for (int i = n4 << 2; i < n; ++i) {
            int v = index[i];
            if (v >= 0) sorted[atomicAdd(&cursor[v], 1)] = i;
        }
    }
}

// Pass 4: gather-reduce. One wave per voxel; 16 lanes x float2 per point,
// 4 points in flight (h = lane>>4). Zero fp32 atomics; fused divide.
__global__ __launch_bounds__(256) void vfe_gather_kernel(
        const float* __restrict__ feat, const int* __restrict__ sorted,
        const int* __restrict__ offs, float* __restrict__ out) {
    const int w = (int)((blockIdx.x * blockDim.x + threadIdx.x) >> 6);
    if (w >= NV) return;
    const int lane = threadIdx.x & 63;
    const int h = lane >> 4;          // 0..3: which point of the group of 4
    const int c2 = lane & 15;         // float2 channel pair
    const int start = offs[w];
    const int end = offs[w + 1];
    float ax = 0.f, ay = 0.f;
    for (int i = start + h; i < end; i += 4) {
        const int p = sorted[i];
        float2 f = reinterpret_cast<const float2*>(feat + (size_t)p * CH)[c2];
        ax += f.x;
        ay += f.y;
    }
    // combine the 4 h-groups: lane c2 += lane c2+32, then += lane c2+16
    ax += __shfl_down(ax, 32);
    ay += __shfl_down(ay, 32);
    ax += __shfl_down(ax, 16);
    ay += __shfl_down(ay, 16);
    if (lane < 16) {
        const float inv = 1.0f / fmaxf((float)(end - start), 1.0f);
        reinterpret_cast<float2*>(out)[(size_t)w * 16 + c2] =
            make_float2(ax * inv, ay * inv);
    }
}

// ---------------- fallback path (round-1): direct fp32 atomics ----------------

__global__ void vfe_scatter_kernel(const float* __restrict__ feat,
                                   const int* __restrict__ index,
                                   float* __restrict__ sums,
                                   float* __restrict__ counts, int n_points) {
    const long long total = (long long)n_points * 8;
    const long long stride = (long long)gridDim.x * blockDim.x;
    for (long long t = (long long)blockIdx.x * blockDim.x + threadIdx.x;
         t < total; t += stride) {
        const int p = (int)(t >> 3);
        const int q = (int)(t & 7);
        const int v = index[p];
        if (v < 0) continue;
        const float4 f = reinterpret_cast<const float4*>(feat)[(long long)p * 8 + q];
        float* dst = sums + (long long)v * CH + q * 4;
        atomicAdd(dst + 0, f.x);
        atomicAdd(dst + 1, f.y);
        atomicAdd(dst + 2, f.z);
        atomicAdd(dst + 3, f.w);
        if (q == 0) atomicAdd(counts + v, 1.0f);
    }
}

__global__ void vfe_finalize_kernel(float* __restrict__ sums,
                                    const float* __restrict__ counts,
                                    int num_voxels) {
    const int total = num_voxels * 8;
    const int stride = gridDim.x * blockDim.x;
    for (int t = blockIdx.x * blockDim.x + threadIdx.x; t < total; t += stride) {
        const int v = t >> 3;
        const float inv = 1.0f / fmaxf(counts[v], 1.0f);
        float4 s = reinterpret_cast<float4*>(sums)[t];
        s.x *= inv; s.y *= inv; s.z *= inv; s.w *= inv;
        reinterpret_cast<float4*>(sums)[t] = s;
    }
}

// ---------------- launcher ----------------

static inline size_t align16(size_t x) { return (x + 15) & ~(size_t)15; }

extern "C" void kernel_launch(void* const* d_in, const int* in_sizes, int n_in,
                              void* d_out, int out_size, void* d_ws, size_t ws_size,
                              hipStream_t stream) {
    const float* feat = (const float*)d_in[0];   // (N, 32) fp32
    const int* index = (const int*)d_in[1];      // (N,) int32
    const int n = in_sizes[1];                   // N = 4,000,000

    float* out = (float*)d_out;                  // (NV, 32) fp32

    // workspace layout (fast path)
    const size_t sz_cnt     = align16((size_t)NV * sizeof(int));
    const size_t sz_offs    = align16(((size_t)NV + 1) * sizeof(int));
    const size_t sz_cursor  = align16((size_t)NV * sizeof(int));
    const size_t sz_part    = align16(128 * sizeof(int));
    const size_t sz_sorted  = align16((size_t)n * sizeof(int));
    const size_t needed = sz_cnt + sz_offs + sz_cursor + sz_part + sz_sorted;

    const int block = 256;

    if (ws_size >= needed) {
        char* ws = (char*)d_ws;
        int* cnt     = (int*)ws;                     ws += sz_cnt;
        int* offs    = (int*)ws;                     ws += sz_offs;
        int* cursor  = (int*)ws;                     ws += sz_cursor;
        int* partials= (int*)ws;                     ws += sz_part;
        int* sorted  = (int*)ws;

        hipMemsetAsync(cnt, 0, (size_t)NV * sizeof(int), stream);

        vfe_hist_kernel<<<2048, block, 0, stream>>>(index, cnt, n);
        vfe_scan1_kernel<<<NSCAN_BLOCKS, 256, 0, stream>>>(cnt, offs, partials, NV);
        vfe_scan2_kernel<<<1, 128, 0, stream>>>(partials, &offs[NV], NSCAN_BLOCKS);
        vfe_scan3_kernel<<<(NV + block - 1) / block, block, 0, stream>>>(
            offs, cursor, partials, NV);
        vfe_permute_kernel<<<2048, block, 0, stream>>>(index, cursor, sorted, n);

        const int waves_per_block = block / 64;
        const int grid_g = (NV + waves_per_block - 1) / waves_per_block;
        vfe_gather_kernel<<<grid_g, block, 0, stream>>>(feat, sorted, offs, out);
    } else {
        // fallback: direct atomic scatter (round-1 path)
        float* counts = (float*)d_ws;
        hipMemsetAsync(out, 0, (size_t)NV * CH * sizeof(float), stream);
        hipMemsetAsync(counts, 0, (size_t)NV * sizeof(float), stream);
        vfe_scatter_kernel<<<4096, block, 0, stream>>>(feat, index, out, counts, n);
        vfe_finalize_kernel<<<(NV * 8 + block - 1) / block, block, 0, stream>>>(
            out, counts, NV);
    }
}